// Round 2
// baseline (13776.956 us; speedup 1.0000x reference)
//
#include <hip/hip_runtime.h>
#include <math.h>

#define NN 716
#define NSQ (716*716)
typedef unsigned short bfu;

__device__ __forceinline__ float b2f(bfu u){ union{unsigned int i; float f;} x; x.i = ((unsigned int)u)<<16; return x.f; }
__device__ __forceinline__ bfu f2b(float f){ union{float fv; unsigned int i;} x; x.fv = f; unsigned int r = (x.i + 0x7fffu + ((x.i>>16)&1u)) >> 16; return (bfu)r; }
__device__ __forceinline__ float sigmoidf_(float x){ return 1.f/(1.f+expf(-x)); }

// ---------------- init / adjacency construction ----------------

__global__ void k_ind(const float* __restrict__ hist, int* __restrict__ ind){
  int b = threadIdx.x; if (b >= 64) return;
  float v = hist[((b*12+11)*NN + 0)*2 + 1];
  ind[b] = ((int)(v*288.0f)) % 288;
}

__global__ void k_dg1(const float* __restrict__ p1, const float* __restrict__ pk,
                      const int* __restrict__ ind, float* __restrict__ tmp1){
  int b = blockIdx.x;
  __shared__ float p1s[40];
  if (threadIdx.x < 40) p1s[threadIdx.x] = p1[ind[b]*40 + threadIdx.x];
  __syncthreads();
  for (int jk = threadIdx.x; jk < 1600; jk += 256){
    float acc = 0.f;
    for (int i = 0; i < 40; ++i) acc += p1s[i]*pk[i*1600 + jk];
    tmp1[b*1600 + jk] = acc;
  }
}

__global__ void k_dg2(const float* __restrict__ p2, const float* __restrict__ tmp1,
                      float* __restrict__ tmp2){
  int b = blockIdx.y;
  __shared__ float ts[1600];
  for (int i = threadIdx.x; i < 1600; i += 256) ts[i] = tmp1[b*1600+i];
  __syncthreads();
  int idx = blockIdx.x*256 + threadIdx.x;
  if (idx >= NN*40) return;
  int n = idx/40, k = idx%40;
  float acc = 0.f;
  for (int j = 0; j < 40; ++j) acc += p2[n*40+j]*ts[j*40+k];
  tmp2[(long)b*NN*40 + idx] = acc;
}

// fused: adp row -> relu -> softmax -> bf16 adjacency row
__global__ __launch_bounds__(256) void k_adjrow(const float* __restrict__ p3,
    const float* __restrict__ tmp2, bfu* __restrict__ adjb){
  int w = blockIdx.x, b = blockIdx.y, tid = threadIdx.x;
  __shared__ float t2s[40];
  __shared__ float red[256];
  if (tid < 40) t2s[tid] = tmp2[((long)b*NN + w)*40 + tid];
  __syncthreads();
  float v[3]; float mx = 0.f;
  #pragma unroll
  for (int q = 0; q < 3; ++q){
    int j = tid + q*256;
    float val = 0.f;
    if (j < NN){
      float acc = 0.f;
      #pragma unroll 8
      for (int k = 0; k < 40; ++k) acc += p3[j*40+k]*t2s[k];
      val = fmaxf(acc, 0.f);
      mx = fmaxf(mx, val);
    }
    v[q] = val;
  }
  red[tid] = mx; __syncthreads();
  for (int s = 128; s > 0; s >>= 1){ if (tid < s) red[tid] = fmaxf(red[tid], red[tid+s]); __syncthreads(); }
  mx = red[0]; __syncthreads();
  float sum = 0.f;
  #pragma unroll
  for (int q = 0; q < 3; ++q){
    int j = tid + q*256;
    if (j < NN){ v[q] = expf(v[q]-mx); sum += v[q]; }
  }
  red[tid] = sum; __syncthreads();
  for (int s = 128; s > 0; s >>= 1){ if (tid < s) red[tid] += red[tid+s]; __syncthreads(); }
  float inv = 1.f/red[0];
  bfu* p = adjb + (long)b*NSQ + (long)w*NN;
  #pragma unroll
  for (int q = 0; q < 3; ++q){ int j = tid + q*256; if (j < NN) p[j] = f2b(v[q]*inv); }
}

// xs[n][t] = sum_b x_a[b,n,t]; y[n] = sum_t xs[n][t]
__global__ void k_xs(const float* __restrict__ hist, const float* __restrict__ saW,
                     const float* __restrict__ sab, float* __restrict__ xs, float* __restrict__ y){
  int n = blockIdx.x, b = threadIdx.x; // 64 threads
  float w = saW[0], bb = sab[0];
  float ytot = 0.f;
  for (int t = 0; t < 13; ++t){
    float inp = (t == 0) ? 0.f : hist[((b*12 + (t-1))*NN + n)*2];
    float s = inp;
    for (int off = 32; off > 0; off >>= 1) s += __shfl_down(s, off, 64);
    if (b == 0){ float val = w*s + 64.f*bb; xs[n*13+t] = val; ytot += val; }
  }
  if (b == 0) y[n] = ytot;
}

__global__ void k_adjp(const float* __restrict__ xs, const float* __restrict__ y,
                       const float* __restrict__ piv, float* __restrict__ adjp){
  int i = blockIdx.y;
  __shared__ float xi[13];
  if (threadIdx.x < 13) xi[threadIdx.x] = xs[i*13+threadIdx.x];
  __syncthreads();
  int j = blockIdx.x*256 + threadIdx.x;
  if (j >= NN) return;
  float acc = 0.f;
  #pragma unroll
  for (int t = 0; t < 12; ++t) acc += xi[t]*xs[j*13+t+1];
  adjp[(long)i*NN+j] = acc / y[j] * piv[(long)i*NN+j];
}

__global__ void k_score(const float* __restrict__ adjp, float* __restrict__ score){
  int n = blockIdx.x, tid = threadIdx.x;
  float s = 0.f;
  for (int i = tid; i < NN; i += 256) s += adjp[(long)i*NN+n] + adjp[(long)n*NN+i];
  __shared__ float red[256];
  red[tid] = s; __syncthreads();
  for (int k = 128; k > 0; k >>= 1){ if (tid < k) red[tid] += red[tid+k]; __syncthreads(); }
  if (tid == 0) score[n] = red[0];
}

// bitonic sort 1024 (desc, tie->lower index first), take top 100 -> mask
__global__ void k_topk(const float* __restrict__ score, int* __restrict__ mask){
  __shared__ float v[1024];
  __shared__ int ix[1024];
  int tid = threadIdx.x;
  for (int t = tid; t < 1024; t += 256){ v[t] = (t < NN) ? score[t] : -INFINITY; ix[t] = t; }
  __syncthreads();
  for (int k = 2; k <= 1024; k <<= 1){
    for (int j = k >> 1; j > 0; j >>= 1){
      for (int t = tid; t < 1024; t += 256){
        int l = t ^ j;
        if (l > t){
          bool up = ((t & k) == 0);
          bool g = (v[t] > v[l]) || (v[t] == v[l] && ix[t] < ix[l]);
          if (up ? !g : g){
            float tv = v[t]; v[t] = v[l]; v[l] = tv;
            int ti = ix[t]; ix[t] = ix[l]; ix[l] = ti;
          }
        }
      }
      __syncthreads();
    }
  }
  for (int t = tid; t < NN; t += 256) mask[t] = 0;
  __syncthreads();
  if (tid < 100) mask[ix[tid]] = 1;
}

// masked relu softmax of adjp rows -> bf16 adjpb
__global__ void k_pivsoftmax(const float* __restrict__ adjp, const int* __restrict__ mask,
                             bfu* __restrict__ adjpb){
  int i = blockIdx.x, tid = threadIdx.x;
  const float* p = adjp + (long)i*NN;
  int mi = mask[i];
  float v[3]; float mx = 0.f;
  #pragma unroll
  for (int q = 0; q < 3; ++q){
    int j = tid + q*256;
    v[q] = (j < NN && mi && mask[j]) ? fmaxf(p[j], 0.f) : 0.f;
    if (j < NN) mx = fmaxf(mx, v[q]);
  }
  __shared__ float red[256];
  red[tid] = mx; __syncthreads();
  for (int s = 128; s > 0; s >>= 1){ if (tid < s) red[tid] = fmaxf(red[tid], red[tid+s]); __syncthreads(); }
  mx = red[0]; __syncthreads();
  float sum = 0.f;
  #pragma unroll
  for (int q = 0; q < 3; ++q){
    int j = tid + q*256;
    if (j < NN){ v[q] = expf(v[q]-mx); sum += v[q]; }
  }
  red[tid] = sum; __syncthreads();
  for (int s = 128; s > 0; s >>= 1){ if (tid < s) red[tid] += red[tid+s]; __syncthreads(); }
  float inv = 1.f/red[0];
  bfu* o = adjpb + (long)i*NN;
  #pragma unroll
  for (int q = 0; q < 3; ++q){ int j = tid + q*256; if (j < NN) o[j] = f2b(v[q]*inv); }
}

// x[b,c,t,n] = start_W[c]*inp + start_b[c]
__global__ void k_init_x(const float* __restrict__ hist, const float* __restrict__ sW,
                         const float* __restrict__ sb, bfu* __restrict__ x){
  int n = blockIdx.x*256 + threadIdx.x; if (n >= NN) return;
  int t = blockIdx.y, b = blockIdx.z;
  float inp = (t == 0) ? 0.f : hist[((b*12 + (t-1))*NN + n)*2];
  #pragma unroll
  for (int c = 0; c < 32; ++c)
    x[((long)(b*32+c)*13 + t)*NN + n] = f2b(sW[c]*inp + sb[c]);
}

// ---------------- per-layer kernels ----------------

// gated temporal conv: fg = tanh(filt)*sigmoid(gate)
__global__ __launch_bounds__(256) void k_fg(const bfu* __restrict__ x,
    const float* __restrict__ fW, const float* __restrict__ fb,
    const float* __restrict__ gW, const float* __restrict__ gb,
    bfu* __restrict__ fg, int layer, int T, int Tp, int d)
{
  __shared__ float wf[2048], wg[2048], bf[32], bg[32];
  for (int i = threadIdx.x; i < 2048; i += 256){ wf[i] = fW[layer*2048+i]; wg[i] = gW[layer*2048+i]; }
  if (threadIdx.x < 32){ bf[threadIdx.x] = fb[layer*32+threadIdx.x]; bg[threadIdx.x] = gb[layer*32+threadIdx.x]; }
  __syncthreads();
  int n = blockIdx.x*256 + threadIdx.x; if (n >= NN) return;
  int t = blockIdx.y, b = blockIdx.z;
  float r0[32], r1[32];
  #pragma unroll
  for (int c = 0; c < 32; ++c){
    long base = ((long)(b*32+c)*T)*NN + n;
    r0[c] = b2f(x[base + (long)t*NN]);
    r1[c] = b2f(x[base + (long)(t+d)*NN]);
  }
  #pragma unroll
  for (int o = 0; o < 32; ++o){
    float f = bf[o], g = bg[o];
    #pragma unroll
    for (int c = 0; c < 32; ++c){
      f += wf[(o*32+c)*2]*r0[c] + wf[(o*32+c)*2+1]*r1[c];
      g += wg[(o*32+c)*2]*r0[c] + wg[(o*32+c)*2+1]*r1[c];
    }
    fg[((long)(b*32+o)*Tp + t)*NN + n] = f2b(tanhf(f)*sigmoidf_(g));
  }
}

// out[o,t,n] = sum_c W[o*96+wofs+c]*in[c,t,n]  (+ add[o,t,n]); t < Tout
__global__ __launch_bounds__(256) void k_cmix(const bfu* __restrict__ in,
    const bfu* __restrict__ add, const float* __restrict__ Wl, int wofs,
    bfu* __restrict__ out, int Tin, int Tout)
{
  __shared__ float w[1024];
  for (int i = threadIdx.x; i < 1024; i += 256) w[i] = Wl[(i>>5)*96 + wofs + (i&31)];
  __syncthreads();
  int n = blockIdx.x*256 + threadIdx.x; if (n >= NN) return;
  int t = blockIdx.y, b = blockIdx.z;
  float vin[32];
  #pragma unroll
  for (int c = 0; c < 32; ++c)
    vin[c] = b2f(in[((long)(b*32+c)*Tin + t)*NN + n]);
  #pragma unroll
  for (int o = 0; o < 32; ++o){
    float acc = 0.f;
    #pragma unroll
    for (int c = 0; c < 32; ++c) acc += w[o*32+c]*vin[c];
    long oidx = ((long)(b*32+o)*Tout + t)*NN + n;
    if (add) acc += b2f(add[oidx]);
    out[oidx] = f2b(acc);
  }
}

// t2[o] = (1-a_s)*(gb[o] + sum_c W0[o,c]*fg[c] + t2[o])   (in place)
__global__ __launch_bounds__(256) void k_fold(const bfu* __restrict__ fg,
    bfu* __restrict__ t2, const float* __restrict__ Wl, const float* __restrict__ gbl,
    const float* __restrict__ alpha, int Tp)
{
  __shared__ float w[1024], bb[32];
  for (int i = threadIdx.x; i < 1024; i += 256) w[i] = Wl[(i>>5)*96 + (i&31)];
  if (threadIdx.x < 32) bb[threadIdx.x] = gbl[threadIdx.x];
  __syncthreads();
  int n = blockIdx.x*256 + threadIdx.x; if (n >= NN) return;
  int t = blockIdx.y, b = blockIdx.z;
  float oma = 1.f - sigmoidf_(alpha[0]);
  float vin[32];
  #pragma unroll
  for (int c = 0; c < 32; ++c)
    vin[c] = b2f(fg[((long)(b*32+c)*Tp + t)*NN + n]);
  #pragma unroll
  for (int o = 0; o < 32; ++o){
    float acc = bb[o];
    #pragma unroll
    for (int c = 0; c < 32; ++c) acc += w[o*32+c]*vin[c];
    long oidx = ((long)(b*32+o)*Tp + t)*NN + n;
    acc += b2f(t2[oidx]);
    t2[oidx] = f2b(oma*acc);
  }
}

// GEMM C[m][w] = sum_v X[m][v]*A[w][v]; all bf16, f32 accumulate
__global__ __launch_bounds__(256) void gemm_nt_bb(const bfu* __restrict__ Xg,
    const bfu* __restrict__ Ag, bfu* __restrict__ Cg,
    int M, long sx, long sa, long sc)
{
  int b = blockIdx.z;
  const bfu* X = Xg + (long)b*sx;
  const bfu* A = Ag + (long)b*sa;
  bfu* C = Cg + (long)b*sc;
  int m0 = blockIdx.y*64, n0 = blockIdx.x*64;
  __shared__ float Xs[16][65], As[16][65];
  int tid = threadIdx.x;
  int lm = tid >> 2, lk = (tid & 3)*4;
  int tx = tid & 15, ty = tid >> 4;
  float acc[4][4] = {};
  for (int k0 = 0; k0 < 716; k0 += 16){
    int m = m0 + lm, n = n0 + lm;
    bool kin = (k0 + lk + 3 < 716);
    if (kin && m < M){
      ushort4 xv = *reinterpret_cast<const ushort4*>(X + (long)m*716 + k0 + lk);
      Xs[lk+0][lm] = b2f(xv.x); Xs[lk+1][lm] = b2f(xv.y); Xs[lk+2][lm] = b2f(xv.z); Xs[lk+3][lm] = b2f(xv.w);
    } else {
      #pragma unroll
      for (int i = 0; i < 4; ++i){ int k = k0+lk+i; Xs[lk+i][lm] = (m < M && k < 716) ? b2f(X[(long)m*716+k]) : 0.f; }
    }
    if (kin && n < 716){
      ushort4 av = *reinterpret_cast<const ushort4*>(A + (long)n*716 + k0 + lk);
      As[lk+0][lm] = b2f(av.x); As[lk+1][lm] = b2f(av.y); As[lk+2][lm] = b2f(av.z); As[lk+3][lm] = b2f(av.w);
    } else {
      #pragma unroll
      for (int i = 0; i < 4; ++i){ int k = k0+lk+i; As[lk+i][lm] = (n < 716 && k < 716) ? b2f(A[(long)n*716+k]) : 0.f; }
    }
    __syncthreads();
    #pragma unroll
    for (int k = 0; k < 16; ++k){
      float av[4], bv[4];
      #pragma unroll
      for (int i = 0; i < 4; ++i) av[i] = Xs[k][ty*4+i];
      #pragma unroll
      for (int j = 0; j < 4; ++j) bv[j] = As[k][tx*4+j];
      #pragma unroll
      for (int i = 0; i < 4; ++i)
        #pragma unroll
        for (int j = 0; j < 4; ++j) acc[i][j] += av[i]*bv[j];
    }
    __syncthreads();
  }
  #pragma unroll
  for (int i = 0; i < 4; ++i){
    int m = m0 + ty*4 + i; if (m >= M) continue;
    int n = n0 + tx*4;
    if (n < 716){
      ushort4 o;
      o.x = f2b(acc[i][0]); o.y = f2b(acc[i][1]); o.z = f2b(acc[i][2]); o.w = f2b(acc[i][3]);
      *reinterpret_cast<ushort4*>(C + (long)m*716 + n) = o;
    }
  }
}

// xn = a_s*(pb + P0*x + xa) + xgpart + residual ; write xn over xa; emit skip slice
__global__ __launch_bounds__(256) void k_combine2(const bfu* __restrict__ x,
    bfu* __restrict__ xa, const bfu* __restrict__ xgp,
    const float* __restrict__ pWl, const float* __restrict__ pbl,
    const float* __restrict__ skWl, const float* __restrict__ skbl,
    const float* __restrict__ alpha, bfu* __restrict__ skip,
    int T, int Tp, int d, int soff)
{
  __shared__ float w[1024], bb[32], sw[256], sb2[8];
  for (int i = threadIdx.x; i < 1024; i += 256) w[i] = pWl[(i>>5)*96 + (i&31)];
  if (threadIdx.x < 32) bb[threadIdx.x] = pbl[threadIdx.x];
  sw[threadIdx.x] = skWl[threadIdx.x];
  if (threadIdx.x < 8) sb2[threadIdx.x] = skbl[threadIdx.x];
  __syncthreads();
  int n = blockIdx.x*256 + threadIdx.x; if (n >= NN) return;
  int t = blockIdx.y, b = blockIdx.z;
  float a_s = sigmoidf_(alpha[0]);
  float xv[32], outv[32];
  #pragma unroll
  for (int c = 0; c < 32; ++c)
    xv[c] = b2f(x[((long)(b*32+c)*T + t)*NN + n]);
  #pragma unroll
  for (int o = 0; o < 32; ++o){
    float acc = bb[o];
    #pragma unroll
    for (int c = 0; c < 32; ++c) acc += w[o*32+c]*xv[c];
    long oidx = ((long)(b*32+o)*Tp + t)*NN + n;
    float xav = b2f(xa[oidx]);
    float xgv = b2f(xgp[oidx]);
    float res = b2f(x[((long)(b*32+o)*T + t + d)*NN + n]);
    outv[o] = a_s*(acc + xav) + xgv + res;
  }
  #pragma unroll
  for (int o = 0; o < 32; ++o)
    xa[((long)(b*32+o)*Tp + t)*NN + n] = f2b(outv[o]);
  #pragma unroll
  for (int sc2 = 0; sc2 < 8; ++sc2){
    float s = sb2[sc2];
    #pragma unroll
    for (int c = 0; c < 32; ++c) s += sw[sc2*32+c]*outv[c];
    skip[((long)b*416 + soff + sc2*Tp + t)*NN + n] = f2b(s);
  }
}

__global__ void k_bn1(const bfu* __restrict__ x, float* __restrict__ red, int Tp){
  int c = blockIdx.y, g = blockIdx.x, tid = threadIdx.x;
  long per = (long)Tp*NN; long cnt = 64L*per;
  float s = 0.f, s2 = 0.f;
  for (long idx = (long)g*256 + tid; idx < cnt; idx += 64L*256){
    long b = idx/per, r = idx - b*per;
    float v = b2f(x[((long)b*32 + c)*per + r]);
    s += v; s2 += v*v;
  }
  __shared__ float rs[256], rs2[256];
  rs[tid] = s; rs2[tid] = s2; __syncthreads();
  for (int k = 128; k > 0; k >>= 1){
    if (tid < k){ rs[tid] += rs[tid+k]; rs2[tid] += rs2[tid+k]; }
    __syncthreads();
  }
  if (tid == 0){ red[(c*64+g)*2] = rs[0]; red[(c*64+g)*2+1] = rs2[0]; }
}

__global__ void k_bn2(const float* __restrict__ red, const float* __restrict__ gamma,
                      const float* __restrict__ beta, float* __restrict__ bnp, int layer, int Tp){
  int c = blockIdx.x;
  if (threadIdx.x != 0) return;
  float s = 0.f, s2 = 0.f;
  for (int g = 0; g < 64; ++g){ s += red[(c*64+g)*2]; s2 += red[(c*64+g)*2+1]; }
  float cnt = 64.f*Tp*716.f;
  float mu = s/cnt, var = s2/cnt - mu*mu;
  float rstd = rsqrtf(var + 1e-5f);
  float ga = gamma[layer*32+c], be = beta[layer*32+c];
  bnp[c*2] = rstd*ga; bnp[c*2+1] = be - mu*rstd*ga;
}

__global__ void k_bnapply(bfu* __restrict__ x, const float* __restrict__ bnp, int Tp){
  long idx = (long)blockIdx.x*256 + threadIdx.x;
  long per = (long)Tp*NN;
  long tot = 64L*32*per;
  if (idx >= tot) return;
  int c = (int)((idx/per) & 31);
  x[idx] = f2b(b2f(x[idx])*bnp[c*2] + bnp[c*2+1]);
}

// ---------------- end MLP ----------------

// H[b][e][n] = relu(b1[e] + sum_k W1[e][k]*relu(S[b][k][n])), M=512,K=416
__global__ __launch_bounds__(256) void gemm_end1(const float* __restrict__ W1,
    const bfu* __restrict__ S, const float* __restrict__ b1, float* __restrict__ H)
{
  int b = blockIdx.z;
  const bfu* Sb = S + (long)b*416*NN;
  float* Hb = H + (long)b*512*NN;
  int m0 = blockIdx.y*64, n0 = blockIdx.x*64;
  __shared__ float As[16][65], Bs[16][65];
  int tid = threadIdx.x;
  int lm = tid >> 2, lk = (tid & 3)*4;
  int lkb = tid >> 6, ln = tid & 63;
  int tx = tid & 15, ty = tid >> 4;
  float acc[4][4] = {};
  for (int k0 = 0; k0 < 416; k0 += 16){
    const float4 av = *reinterpret_cast<const float4*>(W1 + (long)(m0+lm)*416 + k0 + lk);
    As[lk+0][lm] = av.x; As[lk+1][lm] = av.y; As[lk+2][lm] = av.z; As[lk+3][lm] = av.w;
    #pragma unroll
    for (int i = 0; i < 4; ++i){
      int k = k0 + lkb + 4*i;
      int n = n0 + ln;
      Bs[lkb+4*i][ln] = (n < NN) ? fmaxf(b2f(Sb[(long)k*NN + n]), 0.f) : 0.f;
    }
    __syncthreads();
    #pragma unroll
    for (int k = 0; k < 16; ++k){
      float av2[4], bv[4];
      #pragma unroll
      for (int i = 0; i < 4; ++i) av2[i] = As[k][ty*4+i];
      #pragma unroll
      for (int j = 0; j < 4; ++j) bv[j] = Bs[k][tx*4+j];
      #pragma unroll
      for (int i = 0; i < 4; ++i)
        #pragma unroll
        for (int j = 0; j < 4; ++j) acc[i][j] += av2[i]*bv[j];
    }
    __syncthreads();
  }
  #pragma unroll
  for (int i = 0; i < 4; ++i){
    int m = m0 + ty*4 + i;
    float bias = b1[m];
    #pragma unroll
    for (int j = 0; j < 4; ++j){
      int n = n0 + tx*4 + j;
      if (n < NN) Hb[(long)m*NN+n] = fmaxf(acc[i][j] + bias, 0.f);
    }
  }
}

__global__ __launch_bounds__(256) void k_end2(const float* __restrict__ H,
    const float* __restrict__ W2, const float* __restrict__ b2, float* __restrict__ out)
{
  __shared__ float w[12*512];
  for (int i = threadIdx.x; i < 6144; i += 256) w[i] = W2[i];
  __syncthreads();
  int n = blockIdx.x*256 + threadIdx.x; if (n >= NN) return;
  int b = blockIdx.y;
  float acc[12];
  #pragma unroll
  for (int o = 0; o < 12; ++o) acc[o] = b2[o];
  for (int e = 0; e < 512; ++e){
    float h = H[((long)b*512+e)*NN + n];
    #pragma unroll
    for (int o = 0; o < 12; ++o) acc[o] += w[o*512+e]*h;
  }
  #pragma unroll
  for (int o = 0; o < 12; ++o) out[((long)b*12+o)*NN + n] = acc[o];
}

// ---------------- launch ----------------

extern "C" void kernel_launch(void* const* d_in, const int* in_sizes, int n_in,
                              void* d_out, int out_size, void* d_ws, size_t ws_size,
                              hipStream_t stream)
{
  const float* hist = (const float*)d_in[0];
  const float* alpha = (const float*)d_in[1];
  const float* p1  = (const float*)d_in[2];
  const float* p2  = (const float*)d_in[3];
  const float* p3  = (const float*)d_in[4];
  const float* pk  = (const float*)d_in[5];
  const float* piv = (const float*)d_in[6];
  const float* sW  = (const float*)d_in[7];
  const float* sb  = (const float*)d_in[8];
  const float* saW = (const float*)d_in[9];
  const float* sab = (const float*)d_in[10];
  const float* fW  = (const float*)d_in[11];
  const float* fb  = (const float*)d_in[12];
  const float* gW  = (const float*)d_in[13];
  const float* gb  = (const float*)d_in[14];
  const float* skW = (const float*)d_in[15];
  const float* skb = (const float*)d_in[16];
  const float* gcW = (const float*)d_in[17];
  const float* gcb = (const float*)d_in[18];
  const float* pgW = (const float*)d_in[19];
  const float* pgb = (const float*)d_in[20];
  const float* bng = (const float*)d_in[21];
  const float* bnb = (const float*)d_in[22];
  const float* e1W = (const float*)d_in[23];
  const float* e1b = (const float*)d_in[24];
  const float* e2W = (const float*)d_in[25];
  const float* e2b = (const float*)d_in[26];
  float* out = (float*)d_out;

  char* base = (char*)d_ws;
  size_t off = 0;
  auto alloc = [&](size_t bytes)->char*{
    char* r = base + off;
    off = (off + bytes + 255) & ~(size_t)255;
    return r;
  };
  const size_t SZ12 = 64UL*32*12*716*2;   // bf16 chunk, 12 timesteps
  const size_t SZ13 = 64UL*32*13*716*2;   // bf16 chunk, 13 timesteps
  bfu*   t1    = (bfu*)  alloc(SZ12);
  bfu*   t2    = (bfu*)  alloc(SZ12);
  bfu*   adjb  = (bfu*)  alloc(64UL*NSQ*2);
  bfu*   P     = (bfu*)  alloc(SZ13);
  bfu*   Q     = (bfu*)  alloc(SZ12);
  bfu*   skip  = (bfu*)  alloc(64UL*416*716*2);
  float* adjp  = (float*)alloc((size_t)NSQ*4);
  bfu*   adjpb = (bfu*)  alloc((size_t)NSQ*2);
  float* tmp1  = (float*)alloc(64UL*1600*4);
  float* tmp2  = (float*)alloc(64UL*716*40*4);
  float* xs    = (float*)alloc(716UL*13*4);
  float* yv    = (float*)alloc(716UL*4);
  float* score = (float*)alloc(716UL*4);
  float* bnred = (float*)alloc(32UL*64*2*4);
  float* bnp   = (float*)alloc(64UL*4);
  int*   ind   = (int*)  alloc(64UL*4);
  int*   mask  = (int*)  alloc(716UL*4);
  float* hidden = (float*)t1;  // spans t1+t2+adjb = 136.0 MB >= 93.8 MB needed

  // dynamic adjacency
  k_ind<<<1,64,0,stream>>>(hist, ind);
  k_dg1<<<64,256,0,stream>>>(p1, pk, ind, tmp1);
  k_dg2<<<dim3(112,64),256,0,stream>>>(p2, tmp1, tmp2);
  k_adjrow<<<dim3(716,64),256,0,stream>>>(p3, tmp2, adjb);
  // pivotal adjacency
  k_xs<<<716,64,0,stream>>>(hist, saW, sab, xs, yv);
  k_adjp<<<dim3(3,716),256,0,stream>>>(xs, yv, piv, adjp);
  k_score<<<716,256,0,stream>>>(adjp, score);
  k_topk<<<1,256,0,stream>>>(score, mask);
  k_pivsoftmax<<<716,256,0,stream>>>(adjp, mask, adjpb);
  // start conv
  k_init_x<<<dim3(3,13,64),256,0,stream>>>(hist, sW, sb, P);

  int T = 13;
  bfu* x = P;
  bfu* F = Q;
  static const int soff_[8] = {320,240,168,112,64,32,8,0};
  for (int i = 0; i < 8; ++i){
    int d = (i & 1) ? 2 : 1;
    int Tp = T - d;
    dim3 g3(3, Tp, 64);
    k_fg<<<g3,256,0,stream>>>(x, fW, fb, gW, gb, F, i, T, Tp, d);
    // xg path: t2 = (1-a)*(gb + W0g*fg + A*(W1g*fg + A*(W2g*fg)))
    int M1 = 32*Tp; long sx1 = (long)M1*NN;
    dim3 g1(12, (M1+63)/64, 64);
    k_cmix<<<g3,256,0,stream>>>(F, nullptr, gcW + i*3072, 64, t1, Tp, Tp);
    gemm_nt_bb<<<g1,256,0,stream>>>(t1, adjb, t2, M1, sx1, (long)NSQ, sx1);
    k_cmix<<<g3,256,0,stream>>>(F, t2, gcW + i*3072, 32, t1, Tp, Tp);
    gemm_nt_bb<<<g1,256,0,stream>>>(t1, adjb, t2, M1, sx1, (long)NSQ, sx1);
    k_fold<<<g3,256,0,stream>>>(F, t2, gcW + i*3072, gcb + i*32, alpha, Tp);   // F (fg) now dead
    // pgcn path (restricted to t<Tp): F = Ap*(P1p*x + Ap*(P2p*x))
    int M2 = 64*32*Tp;
    dim3 g2(12, M2/64, 1);
    k_cmix<<<g3,256,0,stream>>>(x, nullptr, pgW + i*3072, 64, t1, T, Tp);
    gemm_nt_bb<<<g2,256,0,stream>>>(t1, adjpb, F, M2, 0L, 0L, 0L);
    k_cmix<<<g3,256,0,stream>>>(x, F, pgW + i*3072, 32, t1, T, Tp);
    gemm_nt_bb<<<g2,256,0,stream>>>(t1, adjpb, F, M2, 0L, 0L, 0L);
    // combine + residual + skip; xn written over F
    k_combine2<<<g3,256,0,stream>>>(x, F, t2, pgW + i*3072, pgb + i*32,
        skW + i*256, skb + i*8, alpha, skip, T, Tp, d, soff_[i]);
    // batchnorm
    k_bn1<<<dim3(64,32),256,0,stream>>>(F, bnred, Tp);
    k_bn2<<<32,64,0,stream>>>(bnred, bng, bnb, bnp, i, Tp);
    long tot = 64L*32*Tp*NN;
    k_bnapply<<<(tot+255)/256,256,0,stream>>>(F, bnp, Tp);
    bfu* tmp = x; x = F; F = tmp;
    T = Tp;
  }
  gemm_end1<<<dim3(12,8,64),256,0,stream>>>(e1W, skip, e1b, hidden);
  k_end2<<<dim3(3,64),256,0,stream>>>(hidden, e2W, e2b, out);
}

// Round 3
// 5638.534 us; speedup vs baseline: 2.4434x; 2.4434x over previous
//
#include <hip/hip_runtime.h>
#include <math.h>

#define NN 716
#define NSQ (716*716)
typedef unsigned short bfu;
typedef __attribute__((ext_vector_type(8))) __bf16 bf16x8;
typedef __attribute__((ext_vector_type(4))) float f32x4;

__device__ __forceinline__ float b2f(bfu u){ union{unsigned int i; float f;} x; x.i = ((unsigned int)u)<<16; return x.f; }
__device__ __forceinline__ bfu f2b(float f){ union{float fv; unsigned int i;} x; x.fv = f; unsigned int r = (x.i + 0x7fffu + ((x.i>>16)&1u)) >> 16; return (bfu)r; }
__device__ __forceinline__ float sigmoidf_(float x){ return 1.f/(1.f+expf(-x)); }

// ---------------- init / adjacency construction ----------------

__global__ void k_ind(const float* __restrict__ hist, int* __restrict__ ind){
  int b = threadIdx.x; if (b >= 64) return;
  float v = hist[((b*12+11)*NN + 0)*2 + 1];
  ind[b] = ((int)(v*288.0f)) % 288;
}

__global__ void k_dg1(const float* __restrict__ p1, const float* __restrict__ pk,
                      const int* __restrict__ ind, float* __restrict__ tmp1){
  int b = blockIdx.x;
  __shared__ float p1s[40];
  if (threadIdx.x < 40) p1s[threadIdx.x] = p1[ind[b]*40 + threadIdx.x];
  __syncthreads();
  for (int jk = threadIdx.x; jk < 1600; jk += 256){
    float acc = 0.f;
    for (int i = 0; i < 40; ++i) acc += p1s[i]*pk[i*1600 + jk];
    tmp1[b*1600 + jk] = acc;
  }
}

__global__ void k_dg2(const float* __restrict__ p2, const float* __restrict__ tmp1,
                      float* __restrict__ tmp2){
  int b = blockIdx.y;
  __shared__ float ts[1600];
  for (int i = threadIdx.x; i < 1600; i += 256) ts[i] = tmp1[b*1600+i];
  __syncthreads();
  int idx = blockIdx.x*256 + threadIdx.x;
  if (idx >= NN*40) return;
  int n = idx/40, k = idx%40;
  float acc = 0.f;
  for (int j = 0; j < 40; ++j) acc += p2[n*40+j]*ts[j*40+k];
  tmp2[(long)b*NN*40 + idx] = acc;
}

__global__ void k_p3t(const float* __restrict__ p3, float* __restrict__ p3t){
  int v = blockIdx.x*256 + threadIdx.x; if (v >= NN) return;
  for (int k = 0; k < 40; ++k) p3t[k*NN + v] = p3[v*40 + k];
}

// 8 adjacency rows per block: logits (f32) -> relu -> softmax -> bf16
__global__ __launch_bounds__(256) void k_adjrow8(const float* __restrict__ p3t,
    const float* __restrict__ tmp2, bfu* __restrict__ adjb)
{
  int b = blockIdx.y, w0 = blockIdx.x*8, tid = threadIdx.x;
  __shared__ float t2s[8][40];
  __shared__ float buf[8][720];
  __shared__ float red[256];
  __shared__ float rstat[8];
  for (int i = tid; i < 320; i += 256){
    int r = i/40, k = i%40; int w = w0 + r;
    t2s[r][k] = (w < NN) ? tmp2[((long)b*NN + w)*40 + k] : 0.f;
  }
  __syncthreads();
  float lmax[8] = {0,0,0,0,0,0,0,0};
  for (int q = 0; q < 3; ++q){
    int v = tid + q*256;
    if (v < NN){
      float a[8] = {0,0,0,0,0,0,0,0};
      #pragma unroll 8
      for (int k = 0; k < 40; ++k){
        float pv = p3t[k*NN + v];
        #pragma unroll
        for (int r = 0; r < 8; ++r) a[r] += t2s[r][k]*pv;
      }
      #pragma unroll
      for (int r = 0; r < 8; ++r){
        float val = fmaxf(a[r], 0.f);
        buf[r][v] = val;
        lmax[r] = fmaxf(lmax[r], val);
      }
    }
  }
  #pragma unroll
  for (int r = 0; r < 8; ++r){
    __syncthreads();
    red[tid] = lmax[r]; __syncthreads();
    for (int s = 128; s > 0; s >>= 1){ if (tid < s) red[tid] = fmaxf(red[tid], red[tid+s]); __syncthreads(); }
    if (tid == 0) rstat[r] = red[0];
  }
  __syncthreads();
  float lsum[8] = {0,0,0,0,0,0,0,0};
  for (int q = 0; q < 3; ++q){
    int v = tid + q*256;
    if (v < NN){
      #pragma unroll
      for (int r = 0; r < 8; ++r){
        float e = expf(buf[r][v] - rstat[r]);
        buf[r][v] = e;
        lsum[r] += e;
      }
    }
  }
  #pragma unroll
  for (int r = 0; r < 8; ++r){
    __syncthreads();
    red[tid] = lsum[r]; __syncthreads();
    for (int s = 128; s > 0; s >>= 1){ if (tid < s) red[tid] += red[tid+s]; __syncthreads(); }
    if (tid == 0) rstat[r] = 1.f/red[0];
  }
  __syncthreads();
  for (int q = 0; q < 3; ++q){
    int v = tid + q*256;
    if (v < NN){
      #pragma unroll
      for (int r = 0; r < 8; ++r){
        int w = w0 + r;
        if (w < NN) adjb[(long)b*NSQ + (long)w*NN + v] = f2b(buf[r][v]*rstat[r]);
      }
    }
  }
}

// xs[n][t] = sum_b x_a[b,n,t]; y[n] = sum_t xs[n][t]
__global__ void k_xs(const float* __restrict__ hist, const float* __restrict__ saW,
                     const float* __restrict__ sab, float* __restrict__ xs, float* __restrict__ y){
  int n = blockIdx.x, b = threadIdx.x; // 64 threads
  float w = saW[0], bb = sab[0];
  float ytot = 0.f;
  for (int t = 0; t < 13; ++t){
    float inp = (t == 0) ? 0.f : hist[((b*12 + (t-1))*NN + n)*2];
    float s = inp;
    for (int off = 32; off > 0; off >>= 1) s += __shfl_down(s, off, 64);
    if (b == 0){ float val = w*s + 64.f*bb; xs[n*13+t] = val; ytot += val; }
  }
  if (b == 0) y[n] = ytot;
}

__global__ void k_adjp(const float* __restrict__ xs, const float* __restrict__ y,
                       const float* __restrict__ piv, float* __restrict__ adjp){
  int i = blockIdx.y;
  __shared__ float xi[13];
  if (threadIdx.x < 13) xi[threadIdx.x] = xs[i*13+threadIdx.x];
  __syncthreads();
  int j = blockIdx.x*256 + threadIdx.x;
  if (j >= NN) return;
  float acc = 0.f;
  #pragma unroll
  for (int t = 0; t < 12; ++t) acc += xi[t]*xs[j*13+t+1];
  adjp[(long)i*NN+j] = acc / y[j] * piv[(long)i*NN+j];
}

__global__ void k_score(const float* __restrict__ adjp, float* __restrict__ score){
  int n = blockIdx.x, tid = threadIdx.x;
  float s = 0.f;
  for (int i = tid; i < NN; i += 256) s += adjp[(long)i*NN+n] + adjp[(long)n*NN+i];
  __shared__ float red[256];
  red[tid] = s; __syncthreads();
  for (int k = 128; k > 0; k >>= 1){ if (tid < k) red[tid] += red[tid+k]; __syncthreads(); }
  if (tid == 0) score[n] = red[0];
}

// bitonic sort 1024 (desc, tie->lower index first), take top 100 -> mask
__global__ void k_topk(const float* __restrict__ score, int* __restrict__ mask){
  __shared__ float v[1024];
  __shared__ int ix[1024];
  int tid = threadIdx.x;
  for (int t = tid; t < 1024; t += 256){ v[t] = (t < NN) ? score[t] : -INFINITY; ix[t] = t; }
  __syncthreads();
  for (int k = 2; k <= 1024; k <<= 1){
    for (int j = k >> 1; j > 0; j >>= 1){
      for (int t = tid; t < 1024; t += 256){
        int l = t ^ j;
        if (l > t){
          bool up = ((t & k) == 0);
          bool g = (v[t] > v[l]) || (v[t] == v[l] && ix[t] < ix[l]);
          if (up ? !g : g){
            float tv = v[t]; v[t] = v[l]; v[l] = tv;
            int ti = ix[t]; ix[t] = ix[l]; ix[l] = ti;
          }
        }
      }
      __syncthreads();
    }
  }
  for (int t = tid; t < NN; t += 256) mask[t] = 0;
  __syncthreads();
  if (tid < 100) mask[ix[tid]] = 1;
}

// masked relu softmax of adjp rows -> bf16 adjpb
__global__ void k_pivsoftmax(const float* __restrict__ adjp, const int* __restrict__ mask,
                             bfu* __restrict__ adjpb){
  int i = blockIdx.x, tid = threadIdx.x;
  const float* p = adjp + (long)i*NN;
  int mi = mask[i];
  float v[3]; float mx = 0.f;
  #pragma unroll
  for (int q = 0; q < 3; ++q){
    int j = tid + q*256;
    v[q] = (j < NN && mi && mask[j]) ? fmaxf(p[j], 0.f) : 0.f;
    if (j < NN) mx = fmaxf(mx, v[q]);
  }
  __shared__ float red[256];
  red[tid] = mx; __syncthreads();
  for (int s = 128; s > 0; s >>= 1){ if (tid < s) red[tid] = fmaxf(red[tid], red[tid+s]); __syncthreads(); }
  mx = red[0]; __syncthreads();
  float sum = 0.f;
  #pragma unroll
  for (int q = 0; q < 3; ++q){
    int j = tid + q*256;
    if (j < NN){ v[q] = expf(v[q]-mx); sum += v[q]; }
  }
  red[tid] = sum; __syncthreads();
  for (int s = 128; s > 0; s >>= 1){ if (tid < s) red[tid] += red[tid+s]; __syncthreads(); }
  float inv = 1.f/red[0];
  bfu* o = adjpb + (long)i*NN;
  #pragma unroll
  for (int q = 0; q < 3; ++q){ int j = tid + q*256; if (j < NN) o[j] = f2b(v[q]*inv); }
}

// x[b,c,t,n] = start_W[c]*inp + start_b[c]
__global__ void k_init_x(const float* __restrict__ hist, const float* __restrict__ sW,
                         const float* __restrict__ sb, bfu* __restrict__ x){
  int n = blockIdx.x*256 + threadIdx.x; if (n >= NN) return;
  int t = blockIdx.y, b = blockIdx.z;
  float inp = (t == 0) ? 0.f : hist[((b*12 + (t-1))*NN + n)*2];
  #pragma unroll
  for (int c = 0; c < 32; ++c)
    x[((long)(b*32+c)*13 + t)*NN + n] = f2b(sW[c]*inp + sb[c]);
}

__global__ void k_f2bv(const float* __restrict__ src, bfu* __restrict__ dst, int nelem){
  int i = blockIdx.x*256 + threadIdx.x;
  if (i < nelem) dst[i] = f2b(src[i]);
}

// ---------------- MFMA GEMM: C[m][n] = sum_k X[m][k]*A[n][k], N=716 ----------------
#define LDST 40

__global__ __launch_bounds__(256) void gemm_mfma(const bfu* __restrict__ Xg,
    const bfu* __restrict__ Ag, bfu* __restrict__ Cg,
    int M, int K, long sx, long sa, long sc,
    const float* __restrict__ bias, int relu_out)
{
  const bfu* X = Xg + (long)blockIdx.z*sx;
  const bfu* A = Ag + (long)blockIdx.z*sa;
  bfu*       C = Cg + (long)blockIdx.z*sc;
  int m0 = blockIdx.y*128, n0 = blockIdx.x*128;
  __shared__ bfu Xs[128*LDST];
  __shared__ bfu As[128*LDST];
  int tid = threadIdx.x;
  int wave = tid >> 6, lane = tid & 63;
  int wm = (wave >> 1)*64, wn = (wave & 1)*64;
  int lr = lane & 15, lg = lane >> 4;
  f32x4 acc[4][4] = {};
  int ldr = tid >> 1, ldk = (tid & 1)*16;
  int mg = m0 + ldr, ng = n0 + ldr;
  const bfu* xrow = X + (long)mg*K;
  const bfu* arow = A + (long)ng*K;
  for (int k0 = 0; k0 < K; k0 += 32){
    int kk = k0 + ldk;
    ushort4 z4 = {0,0,0,0};
    ushort4 x0=z4,x1=z4,x2=z4,x3=z4, a0=z4,a1=z4,a2=z4,a3=z4;
    if (mg < M){
      if (kk + 16 <= K){
        const ushort4* s = (const ushort4*)(xrow + kk);
        x0=s[0]; x1=s[1]; x2=s[2]; x3=s[3];
      } else {
        bfu tv[16];
        #pragma unroll
        for (int j=0;j<16;++j) tv[j] = (kk+j < K) ? xrow[kk+j] : (bfu)0;
        const ushort4* s = (const ushort4*)tv;
        x0=s[0]; x1=s[1]; x2=s[2]; x3=s[3];
      }
    }
    if (ng < NN){
      if (kk + 16 <= K){
        const ushort4* s = (const ushort4*)(arow + kk);
        a0=s[0]; a1=s[1]; a2=s[2]; a3=s[3];
      } else {
        bfu tv[16];
        #pragma unroll
        for (int j=0;j<16;++j) tv[j] = (kk+j < K) ? arow[kk+j] : (bfu)0;
        const ushort4* s = (const ushort4*)tv;
        a0=s[0]; a1=s[1]; a2=s[2]; a3=s[3];
      }
    }
    ushort4* xd = (ushort4*)&Xs[ldr*LDST + ldk];
    xd[0]=x0; xd[1]=x1; xd[2]=x2; xd[3]=x3;
    ushort4* ad = (ushort4*)&As[ldr*LDST + ldk];
    ad[0]=a0; ad[1]=a1; ad[2]=a2; ad[3]=a3;
    __syncthreads();
    bf16x8 af[4], bfr[4];
    #pragma unroll
    for (int i=0;i<4;++i){
      af[i]  = *(const bf16x8*)&Xs[(wm + i*16 + lr)*LDST + lg*8];
      bfr[i] = *(const bf16x8*)&As[(wn + i*16 + lr)*LDST + lg*8];
    }
    #pragma unroll
    for (int i=0;i<4;++i)
      #pragma unroll
      for (int j=0;j<4;++j)
        acc[i][j] = __builtin_amdgcn_mfma_f32_16x16x32_bf16(af[i], bfr[j], acc[i][j], 0,0,0);
    __syncthreads();
  }
  #pragma unroll
  for (int i=0;i<4;++i){
    #pragma unroll
    for (int r=0;r<4;++r){
      int m = m0 + wm + i*16 + lg*4 + r;
      if (m >= M) continue;
      float bv = bias ? bias[m] : 0.f;
      #pragma unroll
      for (int j=0;j<4;++j){
        int n = n0 + wn + j*16 + lr;
        if (n < NN){
          float v = acc[i][j][r] + bv;
          if (relu_out) v = fmaxf(v, 0.f);
          C[(long)m*NN + n] = f2b(v);
        }
      }
    }
  }
}

// ---------------- per-layer kernels ----------------

// gated temporal conv: fg = tanh(filt)*sigmoid(gate)
__global__ __launch_bounds__(256) void k_fg(const bfu* __restrict__ x,
    const float* __restrict__ fW, const float* __restrict__ fb,
    const float* __restrict__ gW, const float* __restrict__ gb,
    bfu* __restrict__ fg, int layer, int T, int Tp, int d)
{
  __shared__ float wf[2048], wg[2048], bf[32], bg[32];
  for (int i = threadIdx.x; i < 2048; i += 256){ wf[i] = fW[layer*2048+i]; wg[i] = gW[layer*2048+i]; }
  if (threadIdx.x < 32){ bf[threadIdx.x] = fb[layer*32+threadIdx.x]; bg[threadIdx.x] = gb[layer*32+threadIdx.x]; }
  __syncthreads();
  int n = blockIdx.x*256 + threadIdx.x; if (n >= NN) return;
  int t = blockIdx.y, b = blockIdx.z;
  float r0[32], r1[32];
  #pragma unroll
  for (int c = 0; c < 32; ++c){
    long base = ((long)(b*32+c)*T)*NN + n;
    r0[c] = b2f(x[base + (long)t*NN]);
    r1[c] = b2f(x[base + (long)(t+d)*NN]);
  }
  #pragma unroll
  for (int o = 0; o < 32; ++o){
    float f = bf[o], g = bg[o];
    #pragma unroll
    for (int c = 0; c < 32; ++c){
      f += wf[(o*32+c)*2]*r0[c] + wf[(o*32+c)*2+1]*r1[c];
      g += wg[(o*32+c)*2]*r0[c] + wg[(o*32+c)*2+1]*r1[c];
    }
    fg[((long)(b*32+o)*Tp + t)*NN + n] = f2b(tanhf(f)*sigmoidf_(g));
  }
}

// out[o,t,n] = sum_c W[o*96+wofs+c]*in[c,t,n]  (+ add[o,t,n]); t < Tout
__global__ __launch_bounds__(256) void k_cmix(const bfu* __restrict__ in,
    const bfu* __restrict__ add, const float* __restrict__ Wl, int wofs,
    bfu* __restrict__ out, int Tin, int Tout)
{
  __shared__ float w[1024];
  for (int i = threadIdx.x; i < 1024; i += 256) w[i] = Wl[(i>>5)*96 + wofs + (i&31)];
  __syncthreads();
  int n = blockIdx.x*256 + threadIdx.x; if (n >= NN) return;
  int t = blockIdx.y, b = blockIdx.z;
  float vin[32];
  #pragma unroll
  for (int c = 0; c < 32; ++c)
    vin[c] = b2f(in[((long)(b*32+c)*Tin + t)*NN + n]);
  #pragma unroll
  for (int o = 0; o < 32; ++o){
    float acc = 0.f;
    #pragma unroll
    for (int c = 0; c < 32; ++c) acc += w[o*32+c]*vin[c];
    long oidx = ((long)(b*32+o)*Tout + t)*NN + n;
    if (add) acc += b2f(add[oidx]);
    out[oidx] = f2b(acc);
  }
}

// t2[o] = (1-a_s)*(gb[o] + sum_c W0[o,c]*fg[c] + t2[o])   (in place)
__global__ __launch_bounds__(256) void k_fold(const bfu* __restrict__ fg,
    bfu* __restrict__ t2, const float* __restrict__ Wl, const float* __restrict__ gbl,
    const float* __restrict__ alpha, int Tp)
{
  __shared__ float w[1024], bb[32];
  for (int i = threadIdx.x; i < 1024; i += 256) w[i] = Wl[(i>>5)*96 + (i&31)];
  if (threadIdx.x < 32) bb[threadIdx.x] = gbl[threadIdx.x];
  __syncthreads();
  int n = blockIdx.x*256 + threadIdx.x; if (n >= NN) return;
  int t = blockIdx.y, b = blockIdx.z;
  float oma = 1.f - sigmoidf_(alpha[0]);
  float vin[32];
  #pragma unroll
  for (int c = 0; c < 32; ++c)
    vin[c] = b2f(fg[((long)(b*32+c)*Tp + t)*NN + n]);
  #pragma unroll
  for (int o = 0; o < 32; ++o){
    float acc = bb[o];
    #pragma unroll
    for (int c = 0; c < 32; ++c) acc += w[o*32+c]*vin[c];
    long oidx = ((long)(b*32+o)*Tp + t)*NN + n;
    acc += b2f(t2[oidx]);
    t2[oidx] = f2b(oma*acc);
  }
}

// xn = a_s*(pb + P0*x + xa) + xgpart + residual; write xn over xa; emit transposed relu'd skip
__global__ __launch_bounds__(256) void k_combine2(const bfu* __restrict__ x,
    bfu* __restrict__ xa, const bfu* __restrict__ xgp,
    const float* __restrict__ pWl, const float* __restrict__ pbl,
    const float* __restrict__ skWl, const float* __restrict__ skbl,
    const float* __restrict__ alpha, bfu* __restrict__ skip,
    int T, int Tp, int d, int soff)
{
  __shared__ float w[1024], bb[32], sw[256], sb2[8];
  for (int i = threadIdx.x; i < 1024; i += 256) w[i] = pWl[(i>>5)*96 + (i&31)];
  if (threadIdx.x < 32) bb[threadIdx.x] = pbl[threadIdx.x];
  sw[threadIdx.x] = skWl[threadIdx.x];
  if (threadIdx.x < 8) sb2[threadIdx.x] = skbl[threadIdx.x];
  __syncthreads();
  int n = blockIdx.x*256 + threadIdx.x; if (n >= NN) return;
  int t = blockIdx.y, b = blockIdx.z;
  float a_s = sigmoidf_(alpha[0]);
  float xv[32], outv[32];
  #pragma unroll
  for (int c = 0; c < 32; ++c)
    xv[c] = b2f(x[((long)(b*32+c)*T + t)*NN + n]);
  #pragma unroll
  for (int o = 0; o < 32; ++o){
    float acc = bb[o];
    #pragma unroll
    for (int c = 0; c < 32; ++c) acc += w[o*32+c]*xv[c];
    long oidx = ((long)(b*32+o)*Tp + t)*NN + n;
    float xav = b2f(xa[oidx]);
    float xgv = b2f(xgp[oidx]);
    float res = b2f(x[((long)(b*32+o)*T + t + d)*NN + n]);
    outv[o] = a_s*(acc + xav) + xgv + res;
  }
  #pragma unroll
  for (int o = 0; o < 32; ++o)
    xa[((long)(b*32+o)*Tp + t)*NN + n] = f2b(outv[o]);
  #pragma unroll
  for (int sc2 = 0; sc2 < 8; ++sc2){
    float s = sb2[sc2];
    #pragma unroll
    for (int c = 0; c < 32; ++c) s += sw[sc2*32+c]*outv[c];
    // transposed, pre-relu'd: skip_t[b][n][soff + sc2*Tp + t]
    skip[((long)b*NN + n)*416 + soff + sc2*Tp + t] = f2b(fmaxf(s, 0.f));
  }
}

__global__ void k_bn1(const bfu* __restrict__ x, float* __restrict__ red, int Tp){
  int c = blockIdx.y, g = blockIdx.x, tid = threadIdx.x;
  long per = (long)Tp*NN; long cnt = 64L*per;
  float s = 0.f, s2 = 0.f;
  for (long idx = (long)g*256 + tid; idx < cnt; idx += 64L*256){
    long b = idx/per, r = idx - b*per;
    float v = b2f(x[((long)b*32 + c)*per + r]);
    s += v; s2 += v*v;
  }
  __shared__ float rs[256], rs2[256];
  rs[tid] = s; rs2[tid] = s2; __syncthreads();
  for (int k = 128; k > 0; k >>= 1){
    if (tid < k){ rs[tid] += rs[tid+k]; rs2[tid] += rs2[tid+k]; }
    __syncthreads();
  }
  if (tid == 0){ red[(c*64+g)*2] = rs[0]; red[(c*64+g)*2+1] = rs2[0]; }
}

__global__ void k_bn2(const float* __restrict__ red, const float* __restrict__ gamma,
                      const float* __restrict__ beta, float* __restrict__ bnp, int layer, int Tp){
  int c = blockIdx.x;
  if (threadIdx.x != 0) return;
  float s = 0.f, s2 = 0.f;
  for (int g = 0; g < 64; ++g){ s += red[(c*64+g)*2]; s2 += red[(c*64+g)*2+1]; }
  float cnt = 64.f*Tp*716.f;
  float mu = s/cnt, var = s2/cnt - mu*mu;
  float rstd = rsqrtf(var + 1e-5f);
  float ga = gamma[layer*32+c], be = beta[layer*32+c];
  bnp[c*2] = rstd*ga; bnp[c*2+1] = be - mu*rstd*ga;
}

__global__ void k_bnapply(bfu* __restrict__ x, const float* __restrict__ bnp, int Tp){
  long idx = (long)blockIdx.x*256 + threadIdx.x;
  long per = (long)Tp*NN;
  long tot = 64L*32*per;
  if (idx >= tot) return;
  int c = (int)((idx/per) & 31);
  x[idx] = f2b(b2f(x[idx])*bnp[c*2] + bnp[c*2+1]);
}

// ---------------- end MLP ----------------

__global__ __launch_bounds__(256) void k_end2(const bfu* __restrict__ H,
    const float* __restrict__ W2, const float* __restrict__ b2, float* __restrict__ out)
{
  __shared__ float w[12*512];
  for (int i = threadIdx.x; i < 6144; i += 256) w[i] = W2[i];
  __syncthreads();
  int n = blockIdx.x*256 + threadIdx.x; if (n >= NN) return;
  int b = blockIdx.y;
  float acc[12];
  #pragma unroll
  for (int o = 0; o < 12; ++o) acc[o] = b2[o];
  for (int e = 0; e < 512; ++e){
    float h = b2f(H[((long)b*512+e)*NN + n]);
    #pragma unroll
    for (int o = 0; o < 12; ++o) acc[o] += w[o*512+e]*h;
  }
  #pragma unroll
  for (int o = 0; o < 12; ++o) out[((long)b*12+o)*NN + n] = acc[o];
}

// ---------------- launch ----------------

extern "C" void kernel_launch(void* const* d_in, const int* in_sizes, int n_in,
                              void* d_out, int out_size, void* d_ws, size_t ws_size,
                              hipStream_t stream)
{
  const float* hist = (const float*)d_in[0];
  const float* alpha = (const float*)d_in[1];
  const float* p1  = (const float*)d_in[2];
  const float* p2  = (const float*)d_in[3];
  const float* p3  = (const float*)d_in[4];
  const float* pk  = (const float*)d_in[5];
  const float* piv = (const float*)d_in[6];
  const float* sW  = (const float*)d_in[7];
  const float* sb  = (const float*)d_in[8];
  const float* saW = (const float*)d_in[9];
  const float* sab = (const float*)d_in[10];
  const float* fW  = (const float*)d_in[11];
  const float* fb  = (const float*)d_in[12];
  const float* gW  = (const float*)d_in[13];
  const float* gb  = (const float*)d_in[14];
  const float* skW = (const float*)d_in[15];
  const float* skb = (const float*)d_in[16];
  const float* gcW = (const float*)d_in[17];
  const float* gcb = (const float*)d_in[18];
  const float* pgW = (const float*)d_in[19];
  const float* pgb = (const float*)d_in[20];
  const float* bng = (const float*)d_in[21];
  const float* bnb = (const float*)d_in[22];
  const float* e1W = (const float*)d_in[23];
  const float* e1b = (const float*)d_in[24];
  const float* e2W = (const float*)d_in[25];
  const float* e2b = (const float*)d_in[26];
  float* out = (float*)d_out;

  char* base = (char*)d_ws;
  size_t off = 0;
  auto alloc = [&](size_t bytes)->char*{
    char* r = base + off;
    off = (off + bytes + 255) & ~(size_t)255;
    return r;
  };
  const size_t SZ12 = 64UL*32*12*716*2;   // bf16 chunk, 12 timesteps
  const size_t SZ13 = 64UL*32*13*716*2;   // bf16 chunk, 13 timesteps
  bfu*   t1    = (bfu*)  alloc(SZ12);
  bfu*   t2    = (bfu*)  alloc(SZ12);
  bfu*   adjb  = (bfu*)  alloc(64UL*NSQ*2);
  bfu*   P     = (bfu*)  alloc(SZ13);
  bfu*   Q     = (bfu*)  alloc(SZ12);
  bfu*   skip  = (bfu*)  alloc(64UL*416*716*2);
  float* adjp  = (float*)alloc((size_t)NSQ*4);
  bfu*   adjpb = (bfu*)  alloc((size_t)NSQ*2);
  float* tmp1  = (float*)alloc(64UL*1600*4);
  float* tmp2  = (float*)alloc(64UL*716*40*4);
  float* p3t   = (float*)alloc(40UL*716*4);
  bfu*   e1Wb  = (bfu*)  alloc(512UL*416*2);
  float* xs    = (float*)alloc(716UL*13*4);
  float* yv    = (float*)alloc(716UL*4);
  float* score = (float*)alloc(716UL*4);
  float* bnred = (float*)alloc(32UL*64*2*4);
  float* bnp   = (float*)alloc(64UL*4);
  int*   ind   = (int*)  alloc(64UL*4);
  int*   mask  = (int*)  alloc(716UL*4);
  bfu* hidden = t1;  // 64*512*716*2 = 46.9MB fits t1+t2 (67MB)

  // dynamic adjacency
  k_ind<<<1,64,0,stream>>>(hist, ind);
  k_dg1<<<64,256,0,stream>>>(p1, pk, ind, tmp1);
  k_dg2<<<dim3(112,64),256,0,stream>>>(p2, tmp1, tmp2);
  k_p3t<<<3,256,0,stream>>>(p3, p3t);
  k_adjrow8<<<dim3(90,64),256,0,stream>>>(p3t, tmp2, adjb);
  // pivotal adjacency
  k_xs<<<716,64,0,stream>>>(hist, saW, sab, xs, yv);
  k_adjp<<<dim3(3,716),256,0,stream>>>(xs, yv, piv, adjp);
  k_score<<<716,256,0,stream>>>(adjp, score);
  k_topk<<<1,256,0,stream>>>(score, mask);
  k_pivsoftmax<<<716,256,0,stream>>>(adjp, mask, adjpb);
  // start conv + weight conversion
  k_init_x<<<dim3(3,13,64),256,0,stream>>>(hist, sW, sb, P);
  k_f2bv<<<(512*416+255)/256,256,0,stream>>>(e1W, e1Wb, 512*416);

  int T = 13;
  bfu* x = P;
  bfu* F = Q;
  static const int soff_[8] = {320,240,168,112,64,32,8,0};
  for (int i = 0; i < 8; ++i){
    int d = (i & 1) ? 2 : 1;
    int Tp = T - d;
    dim3 g3(3, Tp, 64);
    k_fg<<<g3,256,0,stream>>>(x, fW, fb, gW, gb, F, i, T, Tp, d);
    // xg path: t2 = (1-a)*(gb + W0g*fg + A*(W1g*fg + A*(W2g*fg)))
    int M1 = 32*Tp; long sx1 = (long)M1*NN;
    dim3 g1(6, (M1+127)/128, 64);
    k_cmix<<<g3,256,0,stream>>>(F, nullptr, gcW + i*3072, 64, t1, Tp, Tp);
    gemm_mfma<<<g1,256,0,stream>>>(t1, adjb, t2, M1, 716, sx1, (long)NSQ, sx1, nullptr, 0);
    k_cmix<<<g3,256,0,stream>>>(F, t2, gcW + i*3072, 32, t1, Tp, Tp);
    gemm_mfma<<<g1,256,0,stream>>>(t1, adjb, t2, M1, 716, sx1, (long)NSQ, sx1, nullptr, 0);
    k_fold<<<g3,256,0,stream>>>(F, t2, gcW + i*3072, gcb + i*32, alpha, Tp);   // F (fg) now dead
    // pgcn path (restricted to t<Tp): F = Ap*(P1p*x + Ap*(P2p*x))
    int M2 = 64*32*Tp;
    dim3 g2(6, (M2+127)/128, 1);
    k_cmix<<<g3,256,0,stream>>>(x, nullptr, pgW + i*3072, 64, t1, T, Tp);
    gemm_mfma<<<g2,256,0,stream>>>(t1, adjpb, F, M2, 716, 0L, 0L, 0L, nullptr, 0);
    k_cmix<<<g3,256,0,stream>>>(x, F, pgW + i*3072, 32, t1, T, Tp);
    gemm_mfma<<<g2,256,0,stream>>>(t1, adjpb, F, M2, 716, 0L, 0L, 0L, nullptr, 0);
    // combine + residual + skip; xn written over F
    k_combine2<<<g3,256,0,stream>>>(x, F, t2, pgW + i*3072, pgb + i*32,
        skW + i*256, skb + i*8, alpha, skip, T, Tp, d, soff_[i]);
    // batchnorm
    k_bn1<<<dim3(64,32),256,0,stream>>>(F, bnred, Tp);
    k_bn2<<<32,64,0,stream>>>(bnred, bng, bnb, bnp, i, Tp);
    long tot = 64L*32*Tp*NN;
    k_bnapply<<<(tot+255)/256,256,0,stream>>>(F, bnp, Tp);
    bfu* tmp = x; x = F; F = tmp;
    T = Tp;
  }
  // end MLP: hidden[b][e][n] = relu(e1b + e1W*relu(skip)); skip stored relu'd/transposed
  gemm_mfma<<<dim3(6,4,64),256,0,stream>>>(e1Wb, skip, hidden, 512, 416,
      0L, 416L*716, 512L*716, e1b, 1);
  k_end2<<<dim3(3,64),256,0,stream>>>(hidden, e2W, e2b, out);
}